// Round 16
// baseline (57.114 us; speedup 1.0000x reference)
//
#include <hip/hip_runtime.h>
#include <math.h>

#define NB 4
#define NN 256
#define MAT (NN*NN)      // 65536
#define BMAT (NB*MAT)    // 262144
#define ALPHA 0.2f

typedef __attribute__((ext_vector_type(8))) __bf16 bf16x8;
typedef __attribute__((ext_vector_type(4))) float f32x4;

union U8 { bf16x8 v; unsigned short u[8]; };

#define MFMA(acc, A, B) acc = __builtin_amdgcn_mfma_f32_16x16x32_bf16(A, B, acc, 0, 0, 0)

// native f32->bf16 RNE conversion (single HW instr, same rounding as the
// prior integer bit-trick -> bit-identical planes)
__device__ __forceinline__ unsigned short f2bf(float x) {
    __bf16 h = (__bf16)x;
    return __builtin_bit_cast(unsigned short, h);
}
__device__ __forceinline__ float bf2f(unsigned short h) {
    return __uint_as_float(((unsigned)h) << 16);
}
__device__ __forceinline__ void split3(float x, unsigned short& a,
                                       unsigned short& b, unsigned short& c) {
    a = f2bf(x); float r = x - bf2f(a);
    b = f2bf(r); r -= bf2f(b);
    c = f2bf(r);
}
__device__ __forceinline__ void split2(float x, unsigned short& a,
                                       unsigned short& b) {
    a = f2bf(x);
    b = f2bf(x - bf2f(a));
}

__device__ __forceinline__ float wave_allsum(float v) {
#pragma unroll
    for (int o = 1; o < 64; o <<= 1) v += __shfl_xor(v, o, 64);
    return v;
}

// ---- k_gh: G = E@wa+ba (+ GT transposed store) AND H = E@wp+bp in one
// block (shared A-side loads/splits). 1024 blocks x 128 thr: one 16x16
// tile per block, wave h owns a K-half; partials combined lo+hi via LDS.
// Per-accumulator MFMA chain order identical to r15 -> G/GT/H bit-identical
// -> adjacency exact-consistent. G and H both 6-term compensated (r7: 3-term
// H shifts layer-1 E enough to flip adjacency -> 2e-2 failures).
template<int L0>
__global__ __launch_bounds__(128) void k_gh(
    const float* __restrict__ Ef,            // layer0 input (f32)
    const unsigned short* __restrict__ Epl,  // layer1 input planes
    const float* __restrict__ Wa, const float* __restrict__ ba,
    const float* __restrict__ Wp, const float* __restrict__ bp,
    float* __restrict__ G, float* __restrict__ GT, float* __restrict__ H)
{
    __shared__ f32x4 partG[64], partH[64];
    int bid = blockIdx.x;
    int b = bid >> 8, t = bid & 255;
    int tm = t >> 4, tn = t & 15;
    int tid = threadIdx.x, h = tid >> 6, lane = tid & 63;
    int l15 = lane & 15, lk = (lane >> 4) * 8, lk4 = lane >> 4;

    f32x4 accG = 0.0f, accH = 0.0f;
    int arow = b * MAT + (tm * 16 + l15) * NN;
    int col = tn * 16 + l15;

    const int TP[6] = {0, 0, 1, 0, 1, 2}, TQ[6] = {0, 1, 0, 2, 1, 0};
#pragma unroll
    for (int ks = 0; ks < 4; ++ks) {
        int kb = h * 128 + ks * 32 + lk;
        U8 aE[3], wvA[3], wvP[3];
        if (L0) {
            f32x4 e0 = *(const f32x4*)&Ef[arow + kb];
            f32x4 e1 = *(const f32x4*)&Ef[arow + kb + 4];
#pragma unroll
            for (int i = 0; i < 4; ++i) {
                split3(e0[i], aE[0].u[i], aE[1].u[i], aE[2].u[i]);
                split3(e1[i], aE[0].u[i + 4], aE[1].u[i + 4], aE[2].u[i + 4]);
            }
        } else {
#pragma unroll
            for (int pp = 0; pp < 3; ++pp)
                aE[pp].v = *(const bf16x8*)&Epl[pp * BMAT + arow + kb];
        }
#pragma unroll
        for (int kk = 0; kk < 8; ++kk) {
            float wf = Wa[(kb + kk) * NN + col];
            split3(wf, wvA[0].u[kk], wvA[1].u[kk], wvA[2].u[kk]);
            float pf = Wp[(kb + kk) * NN + col];
            split3(pf, wvP[0].u[kk], wvP[1].u[kk], wvP[2].u[kk]);
        }
#pragma unroll
        for (int t6 = 0; t6 < 6; ++t6) {
            MFMA(accG, aE[TP[t6]].v, wvA[TQ[t6]].v);
            MFMA(accH, aE[TP[t6]].v, wvP[TQ[t6]].v);
        }
    }
    if (h == 1) { partG[lane] = accG; partH[lane] = accH; }
    __syncthreads();
    if (h == 0) {
        f32x4 hiG = partG[lane], hiH = partH[lane];
        float bav = ba[col], bpv = bp[col];
        f32x4 gv, hv;
#pragma unroll
        for (int r = 0; r < 4; ++r) {
            gv[r] = (accG[r] + hiG[r]) + bav;
            hv[r] = (accH[r] + hiH[r]) + bpv;
        }
#pragma unroll
        for (int r = 0; r < 4; ++r) {
            int row = tm * 16 + lk4 * 4 + r;
            G[b * MAT + row * NN + col] = gv[r];
            H[b * MAT + row * NN + col] = hv[r];
        }
        *(f32x4*)&GT[b * MAT + col * NN + tm * 16 + lk4 * 4] = gv;
    }
}

// ---- k_fsP: fused prep + D/N GEMM pair + divide/fallback + symmetrize.
// grid (136, NB) x 512: wave w -> side=w>>2, quarter=w&3 (64 K-cols each).
// No max-subtraction (L bounded, exp in f32 range; N/D shift-invariant).
// eL/eH 2-split: D/N rel ~2^-18 -- the floor for layer 0 (1-split's ~4e-3
// F error would cascade to ~6e-3 layer-1 G shifts -> mass adjacency flips).
template<int FINAL>
__global__ __launch_bounds__(512) void k_fsP(
    const float* __restrict__ G, const float* __restrict__ GT,
    const float* __restrict__ H, const float* __restrict__ ae,
    unsigned short* __restrict__ Epl, float* __restrict__ out)
{
    __shared__ float Fs[2][16 * 17];
    __shared__ float hst[2][4][16], cst[2][4][16];
    __shared__ f32x4 pD[8][64], pN[8][64];
    int b = blockIdx.y;
    int ti = 0, rem = blockIdx.x;
    while (rem >= 16 - ti) { rem -= 16 - ti; ++ti; }
    int tj = ti + rem;
    int t = threadIdx.x, w = t >> 6, lane = t & 63, l15 = lane & 15, q = lane >> 4;
    int side = w >> 2, quar = w & 3;
    int R = side ? tj : ti, C = side ? ti : tj;

    // S = sum(ae): per-wave, identical deterministic order in every wave
    float sv = 0.f;
#pragma unroll
    for (int k = 0; k < 8; ++k) sv += ae[lane + 64 * k];
    float S = wave_allsum(sv);

    // H rows for R-tile, this wave's K-quarter (cols quar*64 + it*32 + q*8)
    float hrow[2][8];
    int hbase = b * MAT + (R * 16 + l15) * NN + quar * 64;
    float hsum = 0.f;
#pragma unroll
    for (int it = 0; it < 2; ++it) {
        f32x4 h0 = *(const f32x4*)&H[hbase + it * 32 + q * 8];
        f32x4 h1 = *(const f32x4*)&H[hbase + it * 32 + q * 8 + 4];
#pragma unroll
        for (int i = 0; i < 4; ++i) { hrow[it][i] = h0[i]; hrow[it][i + 4] = h1[i]; }
#pragma unroll
        for (int i = 0; i < 8; ++i) hsum += hrow[it][i];
    }
    hsum += __shfl_xor(hsum, 16, 64);
    hsum += __shfl_xor(hsum, 32, 64);
    if (q == 0) hst[side][quar][l15] = hsum;

    // adjacency frags + cnt partial for C-rows, this wave's K-quarter
    float cntp = 0.f;
    bf16x8 adjf[2];
    int gbase = b * MAT + (C * 16 + l15) * NN + quar * 64;
#pragma unroll
    for (int it = 0; it < 2; ++it) {
        f32x4 g0 = *(const f32x4*)&G[gbase + it * 32 + q * 8];
        f32x4 g1 = *(const f32x4*)&G[gbase + it * 32 + q * 8 + 4];
        f32x4 t0 = *(const f32x4*)&GT[gbase + it * 32 + q * 8];
        f32x4 t1 = *(const f32x4*)&GT[gbase + it * 32 + q * 8 + 4];
        U8 a_;
#pragma unroll
        for (int i = 0; i < 4; ++i) {
            bool b0 = (g0[i] + t0[i] > 0.f);
            bool b1 = (g1[i] + t1[i] > 0.f);
            cntp += (b0 ? 1.f : 0.f) + (b1 ? 1.f : 0.f);
            a_.u[i] = b0 ? 0x3F80 : 0;
            a_.u[i + 4] = b1 ? 0x3F80 : 0;
        }
        adjf[it] = a_.v;
    }
    cntp += __shfl_xor(cntp, 16, 64);
    cntp += __shfl_xor(cntp, 32, 64);
    if (q == 0) cst[side][quar][l15] = cntp;

    // D/N MFMA with on-the-fly eL/eH 2-split fragments (quarter-K partials)
    f32x4 aD = 0.f, aN = 0.f;
#pragma unroll
    for (int it = 0; it < 2; ++it) {
        U8 e0, e1, q0, q1;
#pragma unroll
        for (int i = 0; i < 8; ++i) {
            float x = S * hrow[it][i];
            float L = (x > 0.f) ? x : ALPHA * x;
            float e = __expf(L);
            float eh = e * hrow[it][i];
            split2(e,  e0.u[i], e1.u[i]);
            split2(eh, q0.u[i], q1.u[i]);
        }
        MFMA(aD, e0.v, adjf[it]); MFMA(aD, e1.v, adjf[it]);
        MFMA(aN, q0.v, adjf[it]); MFMA(aN, q1.v, adjf[it]);
    }
    pD[w][lane] = aD;
    pN[w][lane] = aN;
    __syncthreads();

    // epilogue on quarter-0 waves (one per side)
    float F[4] = {0.f, 0.f, 0.f, 0.f};
    if (quar == 0) {
        float cntC = ((cst[side][0][l15] + cst[side][1][l15]) +
                      cst[side][2][l15]) + cst[side][3][l15];
#pragma unroll
        for (int r = 0; r < 4; ++r) {
            int m = q * 4 + r;
            float dv = ((pD[4*side][lane][r] + pD[4*side+1][lane][r]) +
                        pD[4*side+2][lane][r]) + pD[4*side+3][lane][r];
            float nv = ((pN[4*side][lane][r] + pN[4*side+1][lane][r]) +
                        pN[4*side+2][lane][r]) + pN[4*side+3][lane][r];
            float rsv = (((hst[side][0][m] + hst[side][1][m]) +
                          hst[side][2][m]) + hst[side][3][m]) * (1.f / 256.f);
            F[r] = (cntC > 0.5f) ? nv / dv : rsv;
            Fs[side][m * 17 + l15] = F[r];
        }
    }
    __syncthreads();
    if (quar == 0) {
#pragma unroll
        for (int r = 0; r < 4; ++r) {
            int m = q * 4 + r;
            float e = 0.5f * (F[r] + Fs[1 ^ side][l15 * 17 + m]);
            int idx = b * MAT + (R * 16 + m) * NN + C * 16 + l15;
            if (FINAL) {
                float tv = tanhf(e);
                out[idx] = tv; out[BMAT + idx] = tv;
            } else {
                unsigned short s0, s1, s2;
                split3(e, s0, s1, s2);
                Epl[idx] = s0; Epl[BMAT + idx] = s1; Epl[2 * BMAT + idx] = s2;
            }
        }
    }
}

extern "C" void kernel_launch(void* const* d_in, const int* in_sizes, int n_in,
                              void* d_out, int out_size, void* d_ws, size_t ws_size,
                              hipStream_t stream) {
    const float* edges = (const float*)d_in[1];
    const float* wp[2] = {(const float*)d_in[7],  (const float*)d_in[17]};
    const float* bp[2] = {(const float*)d_in[8],  (const float*)d_in[18]};
    const float* ae[2] = {(const float*)d_in[9],  (const float*)d_in[19]};
    const float* wa[2] = {(const float*)d_in[10], (const float*)d_in[20]};
    const float* ba[2] = {(const float*)d_in[11], (const float*)d_in[21]};
    float* out = (float*)d_out;

    // ws layout (~4.5 MB)
    unsigned short* EplB = (unsigned short*)d_ws;    // 3 planes (layer-1 input)
    float* G  = (float*)(EplB + 3 * BMAT);           // 1MB
    float* GT = G + BMAT;                            // 1MB
    float* H  = GT + BMAT;                           // 1MB

    k_gh<1><<<1024, 128, 0, stream>>>(edges, nullptr, wa[0], ba[0], wp[0], bp[0],
                                      G, GT, H);
    k_fsP<0><<<dim3(136, NB), 512, 0, stream>>>(G, GT, H, ae[0], EplB, nullptr);
    k_gh<0><<<1024, 128, 0, stream>>>(nullptr, EplB, wa[1], ba[1], wp[1], bp[1],
                                      G, GT, H);
    k_fsP<1><<<dim3(136, NB), 512, 0, stream>>>(G, GT, H, ae[1], nullptr, out);
}

// Round 17
// 49.212 us; speedup vs baseline: 1.1606x; 1.1606x over previous
//
#include <hip/hip_runtime.h>
#include <math.h>

#define NB 4
#define NN 256
#define MAT (NN*NN)      // 65536
#define BMAT (NB*MAT)    // 262144
#define ALPHA 0.2f

typedef __attribute__((ext_vector_type(8))) __bf16 bf16x8;
typedef __attribute__((ext_vector_type(4))) float f32x4;

union U8 { bf16x8 v; unsigned short u[8]; };

#define MFMA(acc, A, B) acc = __builtin_amdgcn_mfma_f32_16x16x32_bf16(A, B, acc, 0, 0, 0)

// native f32->bf16 RNE conversion (single HW instr; same rounding as the
// integer bit-trick used in prior rounds -> bit-identical planes)
__device__ __forceinline__ unsigned short f2bf(float x) {
    __bf16 h = (__bf16)x;
    return __builtin_bit_cast(unsigned short, h);
}
__device__ __forceinline__ float bf2f(unsigned short h) {
    return __uint_as_float(((unsigned)h) << 16);
}
__device__ __forceinline__ void split3(float x, unsigned short& a,
                                       unsigned short& b, unsigned short& c) {
    a = f2bf(x); float r = x - bf2f(a);
    b = f2bf(r); r -= bf2f(b);
    c = f2bf(r);
}
__device__ __forceinline__ void split2(float x, unsigned short& a,
                                       unsigned short& b) {
    a = f2bf(x);
    b = f2bf(x - bf2f(a));
}

__device__ __forceinline__ float wave_allsum(float v) {
#pragma unroll
    for (int o = 1; o < 64; o <<= 1) v += __shfl_xor(v, o, 64);
    return v;
}

// ---- k_gh: G = E@wa+ba (+ GT transposed store), H = E@wp+bp.
// 2048 blocks x 128 thr: one 16x16 tile per block, wave h owns K-half.
// G and H both 6-term compensated (H 6-term is mandatory: 3-term H shifts
// layer-1 E by ~2.5e-4 -> adjacency sign flips -> 2e-2 failures, r7).
// r16 lesson: do NOT merge G and H into one block -- doubling the per-wave
// serial path while halving waves/SIMD regressed 49.3 -> 57.1 us.
template<int L0>
__global__ __launch_bounds__(128) void k_gh(
    const float* __restrict__ Ef,            // layer0 input (f32)
    const unsigned short* __restrict__ Epl,  // layer1 input planes
    const float* __restrict__ Wa, const float* __restrict__ ba,
    const float* __restrict__ Wp, const float* __restrict__ bp,
    float* __restrict__ G, float* __restrict__ GT, float* __restrict__ H)
{
    __shared__ f32x4 part[64];
    int bid = blockIdx.x;
    int m = bid >> 10, b = (bid >> 8) & 3, t = bid & 255;
    int tm = t >> 4, tn = t & 15;
    const float* W = m ? Wp : Wa;
    const float* bias = m ? bp : ba;
    float* C = (m ? H : G) + b * MAT;
    int tid = threadIdx.x, h = tid >> 6, lane = tid & 63;
    int l15 = lane & 15, lk = (lane >> 4) * 8, lk4 = lane >> 4;

    f32x4 acc = 0.0f;
    int arow = b * MAT + (tm * 16 + l15) * NN;
    int col = tn * 16 + l15;

    const int TP[6] = {0, 0, 1, 0, 1, 2}, TQ[6] = {0, 1, 0, 2, 1, 0};
#pragma unroll
    for (int ks = 0; ks < 4; ++ks) {
        int kb = h * 128 + ks * 32 + lk;
        U8 aE[3], wv[3];
        if (L0) {
            f32x4 e0 = *(const f32x4*)&Ef[arow + kb];
            f32x4 e1 = *(const f32x4*)&Ef[arow + kb + 4];
#pragma unroll
            for (int i = 0; i < 4; ++i) {
                split3(e0[i], aE[0].u[i], aE[1].u[i], aE[2].u[i]);
                split3(e1[i], aE[0].u[i + 4], aE[1].u[i + 4], aE[2].u[i + 4]);
            }
        } else {
#pragma unroll
            for (int pp = 0; pp < 3; ++pp)
                aE[pp].v = *(const bf16x8*)&Epl[pp * BMAT + arow + kb];
        }
#pragma unroll
        for (int kk = 0; kk < 8; ++kk) {
            float wf = W[(kb + kk) * NN + col];
            split3(wf, wv[0].u[kk], wv[1].u[kk], wv[2].u[kk]);
        }
#pragma unroll
        for (int t6 = 0; t6 < 6; ++t6)
            MFMA(acc, aE[TP[t6]].v, wv[TQ[t6]].v);
    }
    if (h == 1) part[lane] = acc;
    __syncthreads();
    if (h == 0) {
        f32x4 hi = part[lane];
        float bv = bias[col];
        f32x4 tv;
#pragma unroll
        for (int r = 0; r < 4; ++r) tv[r] = (acc[r] + hi[r]) + bv;
#pragma unroll
        for (int r = 0; r < 4; ++r)
            C[(tm * 16 + lk4 * 4 + r) * NN + col] = tv[r];
        if (m == 0)
            *(f32x4*)&GT[b * MAT + col * NN + tm * 16 + lk4 * 4] = tv;
    }
}

// ---- k_fsP: fused prep + D/N GEMM pair + divide/fallback + symmetrize.
// grid (136, NB) x 512: wave w -> side=w>>2, quarter=w&3 (64 K-cols each).
// No max-subtraction (L in [-O(10),O(10)], exp safely in f32; N/D ratio is
// shift-invariant) -> no pre-MFMA cross-wave dependency, single barrier.
// eL/eH 2-split (all-positive sums, no cancellation; the floor for layer 0:
// 1-split's ~4e-3 F error would cascade to layer-1 adjacency flips).
template<int FINAL>
__global__ __launch_bounds__(512) void k_fsP(
    const float* __restrict__ G, const float* __restrict__ GT,
    const float* __restrict__ H, const float* __restrict__ ae,
    unsigned short* __restrict__ Epl, float* __restrict__ out)
{
    __shared__ float Fs[2][16 * 17];
    __shared__ float hst[2][4][16], cst[2][4][16];
    __shared__ f32x4 pD[8][64], pN[8][64];
    int b = blockIdx.y;
    int ti = 0, rem = blockIdx.x;
    while (rem >= 16 - ti) { rem -= 16 - ti; ++ti; }
    int tj = ti + rem;
    int t = threadIdx.x, w = t >> 6, lane = t & 63, l15 = lane & 15, q = lane >> 4;
    int side = w >> 2, quar = w & 3;
    int R = side ? tj : ti, C = side ? ti : tj;

    // S = sum(ae): per-wave, identical deterministic order in every wave
    float sv = 0.f;
#pragma unroll
    for (int k = 0; k < 8; ++k) sv += ae[lane + 64 * k];
    float S = wave_allsum(sv);

    // H rows for R-tile, this wave's K-quarter (cols quar*64 + it*32 + q*8)
    float hrow[2][8];
    int hbase = b * MAT + (R * 16 + l15) * NN + quar * 64;
    float hsum = 0.f;
#pragma unroll
    for (int it = 0; it < 2; ++it) {
        f32x4 h0 = *(const f32x4*)&H[hbase + it * 32 + q * 8];
        f32x4 h1 = *(const f32x4*)&H[hbase + it * 32 + q * 8 + 4];
#pragma unroll
        for (int i = 0; i < 4; ++i) { hrow[it][i] = h0[i]; hrow[it][i + 4] = h1[i]; }
#pragma unroll
        for (int i = 0; i < 8; ++i) hsum += hrow[it][i];
    }
    hsum += __shfl_xor(hsum, 16, 64);
    hsum += __shfl_xor(hsum, 32, 64);
    if (q == 0) hst[side][quar][l15] = hsum;

    // adjacency frags + cnt partial for C-rows, this wave's K-quarter
    float cntp = 0.f;
    bf16x8 adjf[2];
    int gbase = b * MAT + (C * 16 + l15) * NN + quar * 64;
#pragma unroll
    for (int it = 0; it < 2; ++it) {
        f32x4 g0 = *(const f32x4*)&G[gbase + it * 32 + q * 8];
        f32x4 g1 = *(const f32x4*)&G[gbase + it * 32 + q * 8 + 4];
        f32x4 t0 = *(const f32x4*)&GT[gbase + it * 32 + q * 8];
        f32x4 t1 = *(const f32x4*)&GT[gbase + it * 32 + q * 8 + 4];
        U8 a_;
#pragma unroll
        for (int i = 0; i < 4; ++i) {
            bool b0 = (g0[i] + t0[i] > 0.f);
            bool b1 = (g1[i] + t1[i] > 0.f);
            cntp += (b0 ? 1.f : 0.f) + (b1 ? 1.f : 0.f);
            a_.u[i] = b0 ? 0x3F80 : 0;
            a_.u[i + 4] = b1 ? 0x3F80 : 0;
        }
        adjf[it] = a_.v;
    }
    cntp += __shfl_xor(cntp, 16, 64);
    cntp += __shfl_xor(cntp, 32, 64);
    if (q == 0) cst[side][quar][l15] = cntp;

    // D/N MFMA with on-the-fly eL/eH 2-split fragments (quarter-K partials)
    f32x4 aD = 0.f, aN = 0.f;
#pragma unroll
    for (int it = 0; it < 2; ++it) {
        U8 e0, e1, q0, q1;
#pragma unroll
        for (int i = 0; i < 8; ++i) {
            float x = S * hrow[it][i];
            float L = (x > 0.f) ? x : ALPHA * x;
            float e = __expf(L);
            float eh = e * hrow[it][i];
            split2(e,  e0.u[i], e1.u[i]);
            split2(eh, q0.u[i], q1.u[i]);
        }
        MFMA(aD, e0.v, adjf[it]); MFMA(aD, e1.v, adjf[it]);
        MFMA(aN, q0.v, adjf[it]); MFMA(aN, q1.v, adjf[it]);
    }
    pD[w][lane] = aD;
    pN[w][lane] = aN;
    __syncthreads();

    // epilogue on quarter-0 waves (one per side)
    float F[4] = {0.f, 0.f, 0.f, 0.f};
    if (quar == 0) {
        float cntC = ((cst[side][0][l15] + cst[side][1][l15]) +
                      cst[side][2][l15]) + cst[side][3][l15];
#pragma unroll
        for (int r = 0; r < 4; ++r) {
            int m = q * 4 + r;
            float dv = ((pD[4*side][lane][r] + pD[4*side+1][lane][r]) +
                        pD[4*side+2][lane][r]) + pD[4*side+3][lane][r];
            float nv = ((pN[4*side][lane][r] + pN[4*side+1][lane][r]) +
                        pN[4*side+2][lane][r]) + pN[4*side+3][lane][r];
            float rsv = (((hst[side][0][m] + hst[side][1][m]) +
                          hst[side][2][m]) + hst[side][3][m]) * (1.f / 256.f);
            F[r] = (cntC > 0.5f) ? nv / dv : rsv;
            Fs[side][m * 17 + l15] = F[r];
        }
    }
    __syncthreads();
    if (quar == 0) {
#pragma unroll
        for (int r = 0; r < 4; ++r) {
            int m = q * 4 + r;
            float e = 0.5f * (F[r] + Fs[1 ^ side][l15 * 17 + m]);
            int idx = b * MAT + (R * 16 + m) * NN + C * 16 + l15;
            if (FINAL) {
                float tv = tanhf(e);
                out[idx] = tv; out[BMAT + idx] = tv;
            } else {
                unsigned short s0, s1, s2;
                split3(e, s0, s1, s2);
                Epl[idx] = s0; Epl[BMAT + idx] = s1; Epl[2 * BMAT + idx] = s2;
            }
        }
    }
}

extern "C" void kernel_launch(void* const* d_in, const int* in_sizes, int n_in,
                              void* d_out, int out_size, void* d_ws, size_t ws_size,
                              hipStream_t stream) {
    const float* edges = (const float*)d_in[1];
    const float* wp[2] = {(const float*)d_in[7],  (const float*)d_in[17]};
    const float* bp[2] = {(const float*)d_in[8],  (const float*)d_in[18]};
    const float* ae[2] = {(const float*)d_in[9],  (const float*)d_in[19]};
    const float* wa[2] = {(const float*)d_in[10], (const float*)d_in[20]};
    const float* ba[2] = {(const float*)d_in[11], (const float*)d_in[21]};
    float* out = (float*)d_out;

    // ws layout (~4.5 MB)
    unsigned short* EplB = (unsigned short*)d_ws;    // 3 planes (layer-1 input)
    float* G  = (float*)(EplB + 3 * BMAT);           // 1MB
    float* GT = G + BMAT;                            // 1MB
    float* H  = GT + BMAT;                           // 1MB

    k_gh<1><<<2048, 128, 0, stream>>>(edges, nullptr, wa[0], ba[0], wp[0], bp[0],
                                      G, GT, H);
    k_fsP<0><<<dim3(136, NB), 512, 0, stream>>>(G, GT, H, ae[0], EplB, nullptr);
    k_gh<0><<<2048, 128, 0, stream>>>(nullptr, EplB, wa[1], ba[1], wp[1], bp[1],
                                      G, GT, H);
    k_fsP<1><<<dim3(136, NB), 512, 0, stream>>>(G, GT, H, ae[1], nullptr, out);
}